// Round 12
// baseline (407.454 us; speedup 1.0000x reference)
//
#include <hip/hip_runtime.h>

#define BB   16384
#define NAg  5
#define DD   128
#define HH   128
#define G4   512   // 4*H
#define KC   256   // LS1 + H
#define AA   64
#define CATW 768   // 6*H

typedef __attribute__((ext_vector_type(8))) short bf16x8;
typedef __attribute__((ext_vector_type(4))) float f32x4;

#define DEV static __device__ __forceinline__

DEV unsigned short bf16r(float x){
  unsigned u = __float_as_uint(x);
  unsigned r = (u + 0x7fffu + ((u >> 16) & 1u)) >> 16;
  return (unsigned short)r;
}
// fast sigmoid/tanh: v_rcp_f32 (1 ULP) instead of IEEE division
DEV float sigf(float x){ return __builtin_amdgcn_rcpf(1.0f + __expf(-x)); }
DEV float tanhf_(float x){ return __builtin_fmaf(2.0f, __builtin_amdgcn_rcpf(1.0f + __expf(-2.0f * x)), -1.0f); }

DEV bf16x8 ld8(const unsigned short* p){ return *(const bf16x8*)p; }

DEV bf16x8 cvt8(const float* __restrict__ p){
  const float4* q = (const float4*)p;
  float4 v0 = q[0], v1 = q[1];
  bf16x8 r;
  r[0]=(short)bf16r(v0.x); r[1]=(short)bf16r(v0.y); r[2]=(short)bf16r(v0.z); r[3]=(short)bf16r(v0.w);
  r[4]=(short)bf16r(v1.x); r[5]=(short)bf16r(v1.y); r[6]=(short)bf16r(v1.z); r[7]=(short)bf16r(v1.w);
  return r;
}

// ---------------- prep: pack weights bf16; Wm/Wc -> per-wave reg-frag layout -
// [n][w][q][kt][lane][8]: lane holds W[g=q*128+w*16+(lane&15)][k=kt*32+(lane>>4)*8+e]
__global__ void k_prep(const float* __restrict__ d1w, const float* __restrict__ d2w,
                       const float* __restrict__ mWih, const float* __restrict__ mWhh,
                       const float* __restrict__ mbih, const float* __restrict__ mbhh,
                       const float* __restrict__ cWih, const float* __restrict__ cWhh,
                       const float* __restrict__ cbih, const float* __restrict__ cbhh,
                       unsigned short* d1w_bf, unsigned short* d2w_bf,
                       unsigned short* Wm, unsigned short* Wc, float* bm, float* bc)
{
  const long long TOT = 16384 + 49152 + 655360 + 655360 + 2560 + 2560;
  for (long long i = (long long)blockIdx.x * 256 + threadIdx.x; i < TOT;
       i += (long long)gridDim.x * 256) {
    long long x = i;
    if (x < 16384) { d1w_bf[x] = bf16r(d1w[x]); continue; }
    x -= 16384;
    if (x < 49152) { d2w_bf[x] = bf16r(d2w[x]); continue; }
    x -= 49152;
    if (x < 655360) {
      int e    = (int)(x & 7);
      int lane = (int)((x >> 3) & 63);
      int kt   = (int)((x >> 9) & 7);
      int q    = (int)((x >> 12) & 3);
      int w    = (int)((x >> 14) & 7);
      int n    = (int)(x >> 17);
      int g = q * 128 + w * 16 + (lane & 15);
      int k = kt * 32 + (lane >> 4) * 8 + e;
      Wm[x] = bf16r(k < 128 ? mWih[((size_t)n * 512 + g) * 128 + k]
                            : mWhh[((size_t)n * 512 + g) * 128 + (k - 128)]);
      continue;
    }
    x -= 655360;
    if (x < 655360) {
      int e    = (int)(x & 7);
      int lane = (int)((x >> 3) & 63);
      int kt   = (int)((x >> 9) & 7);
      int q    = (int)((x >> 12) & 3);
      int w    = (int)((x >> 14) & 7);
      int l0   = (int)(x >> 17);
      int g = q * 128 + w * 16 + (lane & 15);
      int k = kt * 32 + (lane >> 4) * 8 + e;
      Wc[x] = bf16r(k < 128 ? cWih[((size_t)l0 * 512 + g) * 128 + k]
                            : cWhh[((size_t)l0 * 512 + g) * 128 + (k - 128)]);
      continue;
    }
    x -= 655360;
    if (x < 2560) { bm[x] = mbih[x] + mbhh[x]; continue; }
    x -= 2560;
    bc[x] = cbih[x] + cbhh[x];
  }
}

// ---------------- obs = input @ d1_w^T + d1_b -> bf16 (n,b,128), staged ------
__global__ __launch_bounds__(256) void k_obs(const float* __restrict__ input,
                                             const unsigned short* __restrict__ d1w,
                                             const float* __restrict__ d1b,
                                             unsigned short* __restrict__ obs_bf)
{
  __shared__ __align__(16) unsigned short ob[64][128];

  const int m0 = blockIdx.x * 64;
  const int w = threadIdx.x >> 6, l = threadIdx.x & 63;
  const int c0l = l & 15, hi = l >> 4;

  const int arow_m = m0 + w * 16 + c0l;           // m = n*B + b
  const int n = arow_m >> 14, b = arow_m & 16383;
  const float* arow = input + ((size_t)b * NAg + n) * DD;

  f32x4 acc[8];
  #pragma unroll
  for (int nt = 0; nt < 8; nt++) acc[nt] = (f32x4){0, 0, 0, 0};

  #pragma unroll
  for (int kt = 0; kt < 4; ++kt) {
    const int k = kt * 32 + hi * 8;
    bf16x8 a = cvt8(arow + k);
    #pragma unroll
    for (int nt = 0; nt < 8; nt++) {
      bf16x8 bfr = ld8(d1w + (size_t)(nt * 16 + c0l) * DD + k);
      acc[nt] = __builtin_amdgcn_mfma_f32_16x16x32_bf16(a, bfr, acc[nt], 0, 0, 0);
    }
  }
  #pragma unroll
  for (int nt = 0; nt < 8; nt++) {
    const int col = nt * 16 + c0l;
    const float bias = d1b[col];
    #pragma unroll
    for (int j = 0; j < 4; j++) {
      const int lr = w * 16 + hi * 4 + j;
      ob[lr][col ^ ((lr & 7) << 3)] = bf16r(acc[nt][j] + bias);
    }
  }
  __syncthreads();
  #pragma unroll
  for (int cc = 0; cc < 4; ++cc) {
    const int idx = cc * 256 + threadIdx.x;
    const int r = idx >> 4;
    const int c8 = (idx & 15) << 3;
    bf16x8 v = *(const bf16x8*)&ob[r][c8 ^ ((r & 7) << 3)];
    *(bf16x8*)(obs_bf + (size_t)(m0 + r) * DD + c8) = v;
  }
}

// ---------------- mem LSTM, reg-W style: 512 thr, W resident -----------------
__global__ __launch_bounds__(512) void k_mem(const unsigned short* __restrict__ obs_bf,
                                             const float* __restrict__ h0,
                                             const float* __restrict__ c0,
                                             const unsigned short* __restrict__ Wmp,
                                             const float* __restrict__ bm,
                                             float* __restrict__ out_h,
                                             float* __restrict__ out_c,
                                             unsigned short* __restrict__ cat)
{
  __shared__ __align__(16) float hs[64][128];   // 32 KB f32 staging

  const int n = blockIdx.x >> 8;
  const int b0 = (blockIdx.x & 255) << 6;
  const int tid = threadIdx.x;
  const int w = tid >> 6, lane = tid & 63;
  const int c0l = lane & 15, hi = lane >> 4;
  const int u = w * 16 + c0l;

  const unsigned short* Wg = Wmp + (size_t)n * 131072 + (size_t)w * 16384 + lane * 8;
  bf16x8 wfr[4][8];
  #pragma unroll
  for (int q = 0; q < 4; q++)
    #pragma unroll
    for (int kt = 0; kt < 8; kt++)
      wfr[q][kt] = ld8(Wg + (q * 8 + kt) * 512);

  const float bI = bm[n * G4 + u];
  const float bF = bm[n * G4 + 128 + u];
  const float bG = bm[n * G4 + 256 + u];
  const float bO = bm[n * G4 + 384 + u];

  float cnr[2][2][4];

  #pragma unroll
  for (int hh = 0; hh < 2; hh++) {
    f32x4 acc[2][4];
    #pragma unroll
    for (int m2 = 0; m2 < 2; m2++)
      #pragma unroll
      for (int q = 0; q < 4; q++) acc[m2][q] = (f32x4){0, 0, 0, 0};

    #pragma unroll
    for (int kt = 0; kt < 8; ++kt) {
      bf16x8 a[2];
      #pragma unroll
      for (int m2 = 0; m2 < 2; m2++) {
        const int r = (hh * 2 + m2) * 16 + c0l;
        if (kt < 4) a[m2] = ld8(obs_bf + ((size_t)n * BB + b0 + r) * DD + kt * 32 + hi * 8);
        else        a[m2] = cvt8(h0 + ((size_t)n * BB + b0 + r) * HH + (kt - 4) * 32 + hi * 8);
      }
      #pragma unroll
      for (int m2 = 0; m2 < 2; m2++)
        #pragma unroll
        for (int q = 0; q < 4; q++)
          acc[m2][q] = __builtin_amdgcn_mfma_f32_16x16x32_bf16(a[m2], wfr[q][kt], acc[m2][q], 0, 0, 0);
    }

    #pragma unroll
    for (int m2 = 0; m2 < 2; m2++) {
      #pragma unroll
      for (int j = 0; j < 4; j++) {
        const int r = hh * 32 + m2 * 16 + hi * 4 + j;
        const float iv = acc[m2][0][j] + bI;
        const float fv = acc[m2][1][j] + bF;
        const float gv = acc[m2][2][j] + bG;
        const float ov = acc[m2][3][j] + bO;
        const float cold = c0[((size_t)n * BB + b0 + r) * HH + u];
        const float cn = sigf(fv) * cold + sigf(iv) * tanhf_(gv);
        const float hn = sigf(ov) * tanhf_(cn);
        cnr[hh][m2][j] = cn;
        hs[r][u ^ ((r & 7) << 3)] = hn;
      }
    }
  }
  __syncthreads();
  // out_h copy (float4, full lines)
  #pragma unroll
  for (int cc = 0; cc < 4; ++cc) {
    const int idx = cc * 512 + tid;
    const int r = idx >> 5;
    const int c4 = (idx & 31) << 2;
    float4 v = *(const float4*)&hs[r][c4 ^ ((r & 7) << 3)];
    *(float4*)(out_h + ((size_t)n * BB + b0 + r) * HH + c4) = v;
  }
  // cat copy (bf16x8, full lines)
  #pragma unroll
  for (int cc = 0; cc < 2; ++cc) {
    const int idx = cc * 512 + tid;
    const int r = idx >> 4;
    const int c8 = (idx & 15) << 3;
    const float* p = &hs[r][c8 ^ ((r & 7) << 3)];
    float4 v0 = *(const float4*)p, v1 = *(const float4*)(p + 4);
    bf16x8 bv;
    bv[0]=(short)bf16r(v0.x); bv[1]=(short)bf16r(v0.y); bv[2]=(short)bf16r(v0.z); bv[3]=(short)bf16r(v0.w);
    bv[4]=(short)bf16r(v1.x); bv[5]=(short)bf16r(v1.y); bv[6]=(short)bf16r(v1.z); bv[7]=(short)bf16r(v1.w);
    *(bf16x8*)(cat + ((size_t)n * BB + b0 + r) * CATW + 640 + c8) = bv;
  }
  __syncthreads();
  // stage c and copy
  #pragma unroll
  for (int hh = 0; hh < 2; hh++)
    #pragma unroll
    for (int m2 = 0; m2 < 2; m2++)
      #pragma unroll
      for (int j = 0; j < 4; j++) {
        const int r = hh * 32 + m2 * 16 + hi * 4 + j;
        hs[r][u ^ ((r & 7) << 3)] = cnr[hh][m2][j];
      }
  __syncthreads();
  #pragma unroll
  for (int cc = 0; cc < 4; ++cc) {
    const int idx = cc * 512 + tid;
    const int r = idx >> 5;
    const int c4 = (idx & 31) << 2;
    float4 v = *(const float4*)&hs[r][c4 ^ ((r & 7) << 3)];
    *(float4*)(out_c + ((size_t)n * BB + b0 + r) * HH + c4) = v;
  }
}

// ---------------- fused com scan: reg-W, ONE barrier/step, deferred cat copy -
// Step t: obs-MFMA(hh0,hh1) | BARRIER | cat-copy(t-1) | h-MFMA+epi(hh0,hh1).
// Hazards: epi t-1 -> (h-read t, cat-read t) via barrier t; cat-read t /
// h-read t -> epi t+1 rewrite via barrier t+1. Final copy after loop barrier.
__global__ __launch_bounds__(512) void k_comf(const unsigned short* __restrict__ obs_bf,
                                              const unsigned short* __restrict__ Wpk,
                                              const float* __restrict__ bc,
                                              unsigned short* __restrict__ cat)
{
  __shared__ __align__(16) unsigned short hl[2][64][128];   // 32 KB

  const int bid = blockIdx.x;
  const int swz = (bid & 7) * 160 + (bid >> 3);   // 1280 = 8*160, bijective
  const int l0 = swz >> 8;
  const int b0 = (swz & 255) << 6;
  const int tid = threadIdx.x;
  const int w = tid >> 6, lane = tid & 63;
  const int c0l = lane & 15, hi = lane >> 4;
  const int u = w * 16 + c0l;

  const unsigned short* Wg = Wpk + (size_t)l0 * 131072 + (size_t)w * 16384 + lane * 8;
  bf16x8 wfr[4][8];
  #pragma unroll
  for (int q = 0; q < 4; q++)
    #pragma unroll
    for (int kt = 0; kt < 8; kt++)
      wfr[q][kt] = ld8(Wg + (q * 8 + kt) * 512);

  const float bI = bc[l0 * G4 + u];
  const float bF = bc[l0 * G4 + 128 + u];
  const float bG = bc[l0 * G4 + 256 + u];
  const float bO = bc[l0 * G4 + 384 + u];

  // zero h(-1) buffer (hl[1], read by t=0; step-0 barrier certifies)
  for (int i = tid; i < 8192; i += 512) ((unsigned short*)hl)[8192 + i] = 0;

  float creg[2][2][4];
  #pragma unroll
  for (int hh = 0; hh < 2; hh++)
    #pragma unroll
    for (int m2 = 0; m2 < 2; m2++)
      #pragma unroll
      for (int j = 0; j < 4; j++) creg[hh][m2][j] = 0.0f;

  int pit = 0;   // it of previous step (for deferred cat copy)

  for (int t = 0; t < 5; ++t) {
    const int it = (t == 4) ? l0 : (t + (t >= l0 ? 1 : 0));
    const unsigned short* obsb = obs_bf + ((size_t)it * BB + b0) * DD;
    const int rbuf = (t + 1) & 1, wbuf = t & 1;

    // obs-part (kt 0..3) for BOTH halves — no LDS dependency, fills the
    // pre-barrier window while other waves finish the previous epilogue.
    f32x4 acc[2][2][4];
    #pragma unroll
    for (int hh = 0; hh < 2; hh++)
      #pragma unroll
      for (int m2 = 0; m2 < 2; m2++)
        #pragma unroll
        for (int q = 0; q < 4; q++) acc[hh][m2][q] = (f32x4){0, 0, 0, 0};

    #pragma unroll
    for (int hh = 0; hh < 2; hh++) {
      #pragma unroll
      for (int kt = 0; kt < 4; ++kt) {
        bf16x8 a[2];
        #pragma unroll
        for (int m2 = 0; m2 < 2; m2++) {
          const int r = (hh * 2 + m2) * 16 + c0l;
          a[m2] = ld8(obsb + (size_t)r * DD + kt * 32 + hi * 8);
        }
        #pragma unroll
        for (int m2 = 0; m2 < 2; m2++)
          #pragma unroll
          for (int q = 0; q < 4; q++)
            acc[hh][m2][q] = __builtin_amdgcn_mfma_f32_16x16x32_bf16(a[m2], wfr[q][kt], acc[hh][m2][q], 0, 0, 0);
      }
    }

    __syncthreads();   // the ONE barrier: hl[rbuf] (epi t-1 / zero-fill) ready

    // deferred cat copy of step t-1 (reads hl[rbuf]; stores drain under MFMAs)
    if (t > 0) {
      unsigned short* catb = cat + ((size_t)pit * BB + b0) * CATW + l0 * 128;
      #pragma unroll
      for (int cc = 0; cc < 2; ++cc) {
        const int idx = cc * 512 + tid;
        const int r = idx >> 4;
        const int c8 = (idx & 15) << 3;
        bf16x8 v = *(const bf16x8*)&hl[rbuf][r][c8 ^ ((r & 7) << 3)];
        *(bf16x8*)(catb + (size_t)r * CATW + c8) = v;
      }
    }

    // h-part + epilogue per half
    #pragma unroll
    for (int hh = 0; hh < 2; hh++) {
      #pragma unroll
      for (int kt = 4; kt < 8; ++kt) {
        bf16x8 a[2];
        #pragma unroll
        for (int m2 = 0; m2 < 2; m2++) {
          const int r = (hh * 2 + m2) * 16 + c0l;
          a[m2] = ld8(&hl[rbuf][r][((kt - 4) * 32 + hi * 8) ^ ((r & 7) << 3)]);
        }
        #pragma unroll
        for (int m2 = 0; m2 < 2; m2++)
          #pragma unroll
          for (int q = 0; q < 4; q++)
            acc[hh][m2][q] = __builtin_amdgcn_mfma_f32_16x16x32_bf16(a[m2], wfr[q][kt], acc[hh][m2][q], 0, 0, 0);
      }

      #pragma unroll
      for (int m2 = 0; m2 < 2; m2++) {
        #pragma unroll
        for (int j = 0; j < 4; j++) {
          const int r = hh * 32 + m2 * 16 + hi * 4 + j;
          const float iv = acc[hh][m2][0][j] + bI;
          const float fv = acc[hh][m2][1][j] + bF;
          const float gv = acc[hh][m2][2][j] + bG;
          const float ov = acc[hh][m2][3][j] + bO;
          const float cn = sigf(fv) * creg[hh][m2][j] + sigf(iv) * tanhf_(gv);
          const float hn = sigf(ov) * tanhf_(cn);
          creg[hh][m2][j] = cn;
          hl[wbuf][r][u ^ ((r & 7) << 3)] = bf16r(hn);
        }
      }
    }
    pit = it;
  }

  __syncthreads();
  // final cat copy (step 4, wbuf = 0)
  {
    unsigned short* catb = cat + ((size_t)pit * BB + b0) * CATW + l0 * 128;
    #pragma unroll
    for (int cc = 0; cc < 2; ++cc) {
      const int idx = cc * 512 + tid;
      const int r = idx >> 4;
      const int c8 = (idx & 15) << 3;
      bf16x8 v = *(const bf16x8*)&hl[0][r][c8 ^ ((r & 7) << 3)];
      *(bf16x8*)(catb + (size_t)r * CATW + c8) = v;
    }
  }
}

// ---------------- outs = cat @ d2_w^T + d2_b, 128 rows/block -----------------
__global__ __launch_bounds__(256) void k_d2(const unsigned short* __restrict__ cat,
                                            const unsigned short* __restrict__ d2w,
                                            const float* __restrict__ d2b,
                                            float* __restrict__ out)
{
  const int m0 = blockIdx.x * 128;
  const int w = threadIdx.x >> 6, l = threadIdx.x & 63;
  const int c0l = l & 15, hi = l >> 4;

  const unsigned short* arow0 = cat + (size_t)(m0 + w * 16 + c0l) * CATW;
  const unsigned short* arow1 = arow0 + (size_t)64 * CATW;
  f32x4 acc[2][4];
  #pragma unroll
  for (int mt = 0; mt < 2; mt++)
    #pragma unroll
    for (int nt = 0; nt < 4; nt++) acc[mt][nt] = (f32x4){0, 0, 0, 0};

  #pragma unroll 4
  for (int kt = 0; kt < 24; ++kt) {
    const int k = kt * 32 + hi * 8;
    bf16x8 a0 = ld8(arow0 + k);
    bf16x8 a1 = ld8(arow1 + k);
    #pragma unroll
    for (int nt = 0; nt < 4; nt++) {
      bf16x8 bfr = ld8(d2w + (size_t)(nt * 16 + c0l) * CATW + k);
      acc[0][nt] = __builtin_amdgcn_mfma_f32_16x16x32_bf16(a0, bfr, acc[0][nt], 0, 0, 0);
      acc[1][nt] = __builtin_amdgcn_mfma_f32_16x16x32_bf16(a1, bfr, acc[1][nt], 0, 0, 0);
    }
  }
  #pragma unroll
  for (int mt = 0; mt < 2; mt++) {
    #pragma unroll
    for (int nt = 0; nt < 4; nt++) {
      const int col = nt * 16 + c0l;
      const float bias = d2b[col];
      #pragma unroll
      for (int j = 0; j < 4; j++) {
        const int r = m0 + mt * 64 + w * 16 + hi * 4 + j;
        out[(size_t)r * AA + col] = acc[mt][nt][j] + bias;
      }
    }
  }
}

extern "C" void kernel_launch(void* const* d_in, const int* in_sizes, int n_in,
                              void* d_out, int out_size, void* d_ws, size_t ws_size,
                              hipStream_t stream)
{
  const float* input = (const float*)d_in[0];
  const float* h0    = (const float*)d_in[1];
  const float* c0    = (const float*)d_in[2];
  const float* d1w   = (const float*)d_in[3];
  const float* d1b   = (const float*)d_in[4];
  const float* d2w   = (const float*)d_in[5];
  const float* d2b   = (const float*)d_in[6];
  const float* mWih  = (const float*)d_in[7];
  const float* mWhh  = (const float*)d_in[8];
  const float* mbih  = (const float*)d_in[9];
  const float* mbhh  = (const float*)d_in[10];
  const float* cWih  = (const float*)d_in[11];
  const float* cWhh  = (const float*)d_in[12];
  const float* cbih  = (const float*)d_in[13];
  const float* cbhh  = (const float*)d_in[14];
  float* out = (float*)d_out;

  char* ws = (char*)d_ws;
  size_t off = 0;
  auto alloc = [&](size_t bytes) { void* p = ws + off; off += (bytes + 255) & ~255ull; return p; };
  unsigned short* d1w_bf = (unsigned short*)alloc(16384 * 2);
  unsigned short* d2w_bf = (unsigned short*)alloc(49152 * 2);
  unsigned short* Wm     = (unsigned short*)alloc(655360 * 2);
  unsigned short* Wcb    = (unsigned short*)alloc(655360 * 2);
  float* bm              = (float*)alloc(2560 * 4);
  float* bc              = (float*)alloc(2560 * 4);
  unsigned short* obs_bf = (unsigned short*)alloc((size_t)NAg * BB * DD * 2);
  unsigned short* cat    = (unsigned short*)alloc((size_t)NAg * BB * CATW * 2);

  float* out_h = out + (size_t)NAg * BB * AA;
  float* out_c = out_h + (size_t)NAg * BB * HH;

  k_prep<<<2048, 256, 0, stream>>>(d1w, d2w, mWih, mWhh, mbih, mbhh,
                                   cWih, cWhh, cbih, cbhh,
                                   d1w_bf, d2w_bf, Wm, Wcb, bm, bc);
  k_obs<<<(NAg * BB) / 64, 256, 0, stream>>>(input, d1w_bf, d1b, obs_bf);
  k_mem<<<(NAg * BB) / 64, 512, 0, stream>>>(obs_bf, h0, c0, Wm, bm, out_h, out_c, cat);
  k_comf<<<(NAg * BB) / 64, 512, 0, stream>>>(obs_bf, Wcb, bc, cat);
  k_d2<<<(NAg * BB) / 128, 256, 0, stream>>>(cat, d2w_bf, d2b, out);
}

// Round 14
// 334.266 us; speedup vs baseline: 1.2190x; 1.2190x over previous
//
#include <hip/hip_runtime.h>

#define BB   16384
#define NAg  5
#define DD   128
#define HH   128
#define G4   512   // 4*H
#define KC   256   // LS1 + H
#define AA   64
#define CATW 768   // 6*H

typedef __attribute__((ext_vector_type(8))) short bf16x8;
typedef __attribute__((ext_vector_type(4))) float f32x4;

#define DEV static __device__ __forceinline__

DEV unsigned short bf16r(float x){
  unsigned u = __float_as_uint(x);
  unsigned r = (u + 0x7fffu + ((u >> 16) & 1u)) >> 16;
  return (unsigned short)r;
}
// fast sigmoid/tanh: v_rcp_f32 (1 ULP) instead of IEEE division
DEV float sigf(float x){ return __builtin_amdgcn_rcpf(1.0f + __expf(-x)); }
DEV float tanhf_(float x){ return __builtin_fmaf(2.0f, __builtin_amdgcn_rcpf(1.0f + __expf(-2.0f * x)), -1.0f); }

DEV bf16x8 ld8(const unsigned short* p){ return *(const bf16x8*)p; }

DEV bf16x8 cvt8(const float* __restrict__ p){
  const float4* q = (const float4*)p;
  float4 v0 = q[0], v1 = q[1];
  bf16x8 r;
  r[0]=(short)bf16r(v0.x); r[1]=(short)bf16r(v0.y); r[2]=(short)bf16r(v0.z); r[3]=(short)bf16r(v0.w);
  r[4]=(short)bf16r(v1.x); r[5]=(short)bf16r(v1.y); r[6]=(short)bf16r(v1.z); r[7]=(short)bf16r(v1.w);
  return r;
}

// ---------------- prep: pack weights bf16; Wm/Wc -> per-wave reg-frag layout -
// [n][w][q][kt][lane][8]: lane holds W[g=q*128+w*16+(lane&15)][k=kt*32+(lane>>4)*8+e]
__global__ void k_prep(const float* __restrict__ d1w, const float* __restrict__ d2w,
                       const float* __restrict__ mWih, const float* __restrict__ mWhh,
                       const float* __restrict__ mbih, const float* __restrict__ mbhh,
                       const float* __restrict__ cWih, const float* __restrict__ cWhh,
                       const float* __restrict__ cbih, const float* __restrict__ cbhh,
                       unsigned short* d1w_bf, unsigned short* d2w_bf,
                       unsigned short* Wm, unsigned short* Wc, float* bm, float* bc)
{
  const long long TOT = 16384 + 49152 + 655360 + 655360 + 2560 + 2560;
  for (long long i = (long long)blockIdx.x * 256 + threadIdx.x; i < TOT;
       i += (long long)gridDim.x * 256) {
    long long x = i;
    if (x < 16384) { d1w_bf[x] = bf16r(d1w[x]); continue; }
    x -= 16384;
    if (x < 49152) { d2w_bf[x] = bf16r(d2w[x]); continue; }
    x -= 49152;
    if (x < 655360) {
      int e    = (int)(x & 7);
      int lane = (int)((x >> 3) & 63);
      int kt   = (int)((x >> 9) & 7);
      int q    = (int)((x >> 12) & 3);
      int w    = (int)((x >> 14) & 7);
      int n    = (int)(x >> 17);
      int g = q * 128 + w * 16 + (lane & 15);
      int k = kt * 32 + (lane >> 4) * 8 + e;
      Wm[x] = bf16r(k < 128 ? mWih[((size_t)n * 512 + g) * 128 + k]
                            : mWhh[((size_t)n * 512 + g) * 128 + (k - 128)]);
      continue;
    }
    x -= 655360;
    if (x < 655360) {
      int e    = (int)(x & 7);
      int lane = (int)((x >> 3) & 63);
      int kt   = (int)((x >> 9) & 7);
      int q    = (int)((x >> 12) & 3);
      int w    = (int)((x >> 14) & 7);
      int l0   = (int)(x >> 17);
      int g = q * 128 + w * 16 + (lane & 15);
      int k = kt * 32 + (lane >> 4) * 8 + e;
      Wc[x] = bf16r(k < 128 ? cWih[((size_t)l0 * 512 + g) * 128 + k]
                            : cWhh[((size_t)l0 * 512 + g) * 128 + (k - 128)]);
      continue;
    }
    x -= 655360;
    if (x < 2560) { bm[x] = mbih[x] + mbhh[x]; continue; }
    x -= 2560;
    bc[x] = cbih[x] + cbhh[x];
  }
}

// ---------------- obs -> bf16, stored SWIZZLED per 64-row tile ---------------
// obs_glob[tile][r][c] = logical[tile][r][c ^ ((r&7)<<3)]
__global__ __launch_bounds__(256) void k_obs(const float* __restrict__ input,
                                             const unsigned short* __restrict__ d1w,
                                             const float* __restrict__ d1b,
                                             unsigned short* __restrict__ obs_bf)
{
  __shared__ __align__(16) unsigned short ob[64][128];

  const int m0 = blockIdx.x * 64;
  const int w = threadIdx.x >> 6, l = threadIdx.x & 63;
  const int c0l = l & 15, hi = l >> 4;

  const int arow_m = m0 + w * 16 + c0l;           // m = n*B + b
  const int n = arow_m >> 14, b = arow_m & 16383;
  const float* arow = input + ((size_t)b * NAg + n) * DD;

  f32x4 acc[8];
  #pragma unroll
  for (int nt = 0; nt < 8; nt++) acc[nt] = (f32x4){0, 0, 0, 0};

  #pragma unroll
  for (int kt = 0; kt < 4; ++kt) {
    const int k = kt * 32 + hi * 8;
    bf16x8 a = cvt8(arow + k);
    #pragma unroll
    for (int nt = 0; nt < 8; nt++) {
      bf16x8 bfr = ld8(d1w + (size_t)(nt * 16 + c0l) * DD + k);
      acc[nt] = __builtin_amdgcn_mfma_f32_16x16x32_bf16(a, bfr, acc[nt], 0, 0, 0);
    }
  }
  #pragma unroll
  for (int nt = 0; nt < 8; nt++) {
    const int col = nt * 16 + c0l;
    const float bias = d1b[col];
    #pragma unroll
    for (int j = 0; j < 4; j++) {
      const int lr = w * 16 + hi * 4 + j;
      ob[lr][col ^ ((lr & 7) << 3)] = bf16r(acc[nt][j] + bias);
    }
  }
  __syncthreads();
  // store LDS linearly -> obs stays swizzled in global
  #pragma unroll
  for (int cc = 0; cc < 4; ++cc) {
    const int idx = cc * 256 + threadIdx.x;
    const int r = idx >> 4;
    const int c8 = (idx & 15) << 3;
    bf16x8 v = *(const bf16x8*)&ob[r][c8];
    *(bf16x8*)(obs_bf + (size_t)(m0 + r) * DD + c8) = v;
  }
}

// ---------------- mem LSTM, reg-W style (obs read with swizzle XOR) ----------
__global__ __launch_bounds__(512) void k_mem(const unsigned short* __restrict__ obs_bf,
                                             const float* __restrict__ h0,
                                             const float* __restrict__ c0,
                                             const unsigned short* __restrict__ Wmp,
                                             const float* __restrict__ bm,
                                             float* __restrict__ out_h,
                                             float* __restrict__ out_c,
                                             unsigned short* __restrict__ cat)
{
  __shared__ __align__(16) float hs[64][128];   // 32 KB f32 staging

  const int n = blockIdx.x >> 8;
  const int b0 = (blockIdx.x & 255) << 6;
  const int tid = threadIdx.x;
  const int w = tid >> 6, lane = tid & 63;
  const int c0l = lane & 15, hi = lane >> 4;
  const int u = w * 16 + c0l;

  const unsigned short* Wg = Wmp + (size_t)n * 131072 + (size_t)w * 16384 + lane * 8;
  bf16x8 wfr[4][8];
  #pragma unroll
  for (int q = 0; q < 4; q++)
    #pragma unroll
    for (int kt = 0; kt < 8; kt++)
      wfr[q][kt] = ld8(Wg + (q * 8 + kt) * 512);

  const float bI = bm[n * G4 + u];
  const float bF = bm[n * G4 + 128 + u];
  const float bG = bm[n * G4 + 256 + u];
  const float bO = bm[n * G4 + 384 + u];

  float cnr[2][2][4];

  #pragma unroll
  for (int hh = 0; hh < 2; hh++) {
    f32x4 acc[2][4];
    #pragma unroll
    for (int m2 = 0; m2 < 2; m2++)
      #pragma unroll
      for (int q = 0; q < 4; q++) acc[m2][q] = (f32x4){0, 0, 0, 0};

    #pragma unroll
    for (int kt = 0; kt < 8; ++kt) {
      bf16x8 a[2];
      #pragma unroll
      for (int m2 = 0; m2 < 2; m2++) {
        const int r = (hh * 2 + m2) * 16 + c0l;
        if (kt < 4) a[m2] = ld8(obs_bf + ((size_t)n * BB + b0 + r) * DD + ((kt * 32 + hi * 8) ^ ((r & 7) << 3)));
        else        a[m2] = cvt8(h0 + ((size_t)n * BB + b0 + r) * HH + (kt - 4) * 32 + hi * 8);
      }
      #pragma unroll
      for (int m2 = 0; m2 < 2; m2++)
        #pragma unroll
        for (int q = 0; q < 4; q++)
          acc[m2][q] = __builtin_amdgcn_mfma_f32_16x16x32_bf16(a[m2], wfr[q][kt], acc[m2][q], 0, 0, 0);
    }

    #pragma unroll
    for (int m2 = 0; m2 < 2; m2++) {
      #pragma unroll
      for (int j = 0; j < 4; j++) {
        const int r = hh * 32 + m2 * 16 + hi * 4 + j;
        const float iv = acc[m2][0][j] + bI;
        const float fv = acc[m2][1][j] + bF;
        const float gv = acc[m2][2][j] + bG;
        const float ov = acc[m2][3][j] + bO;
        const float cold = c0[((size_t)n * BB + b0 + r) * HH + u];
        const float cn = sigf(fv) * cold + sigf(iv) * tanhf_(gv);
        const float hn = sigf(ov) * tanhf_(cn);
        cnr[hh][m2][j] = cn;
        hs[r][u ^ ((r & 7) << 3)] = hn;
      }
    }
  }
  __syncthreads();
  // out_h copy (float4, full lines)
  #pragma unroll
  for (int cc = 0; cc < 4; ++cc) {
    const int idx = cc * 512 + tid;
    const int r = idx >> 5;
    const int c4 = (idx & 31) << 2;
    float4 v = *(const float4*)&hs[r][c4 ^ ((r & 7) << 3)];
    *(float4*)(out_h + ((size_t)n * BB + b0 + r) * HH + c4) = v;
  }
  // cat copy (bf16x8, full lines)
  #pragma unroll
  for (int cc = 0; cc < 2; ++cc) {
    const int idx = cc * 512 + tid;
    const int r = idx >> 4;
    const int c8 = (idx & 15) << 3;
    const float* p = &hs[r][c8 ^ ((r & 7) << 3)];
    float4 v0 = *(const float4*)p, v1 = *(const float4*)(p + 4);
    bf16x8 bv;
    bv[0]=(short)bf16r(v0.x); bv[1]=(short)bf16r(v0.y); bv[2]=(short)bf16r(v0.z); bv[3]=(short)bf16r(v0.w);
    bv[4]=(short)bf16r(v1.x); bv[5]=(short)bf16r(v1.y); bv[6]=(short)bf16r(v1.z); bv[7]=(short)bf16r(v1.w);
    *(bf16x8*)(cat + ((size_t)n * BB + b0 + r) * CATW + 640 + c8) = bv;
  }
  __syncthreads();
  // stage c and copy
  #pragma unroll
  for (int hh = 0; hh < 2; hh++)
    #pragma unroll
    for (int m2 = 0; m2 < 2; m2++)
      #pragma unroll
      for (int j = 0; j < 4; j++) {
        const int r = hh * 32 + m2 * 16 + hi * 4 + j;
        hs[r][u ^ ((r & 7) << 3)] = cnr[hh][m2][j];
      }
  __syncthreads();
  #pragma unroll
  for (int cc = 0; cc < 4; ++cc) {
    const int idx = cc * 512 + tid;
    const int r = idx >> 5;
    const int c4 = (idx & 31) << 2;
    float4 v = *(const float4*)&hs[r][c4 ^ ((r & 7) << 3)];
    *(float4*)(out_c + ((size_t)n * BB + b0 + r) * HH + c4) = v;
  }
}

// ---------------- fused com scan: reg-W + obs LDS prefetch (r11 schedule) ----
__global__ __launch_bounds__(512) void k_comf(const unsigned short* __restrict__ obs_bf,
                                              const unsigned short* __restrict__ Wpk,
                                              const float* __restrict__ bc,
                                              unsigned short* __restrict__ cat)
{
  __shared__ __align__(16) unsigned short hl[2][64][128];   // 32 KB
  __shared__ __align__(16) unsigned short ol[2][64][128];   // 32 KB obs dbuf

  const int bid = blockIdx.x;
  const int swz = (bid & 7) * 160 + (bid >> 3);   // 1280 = 8*160, bijective
  const int l0 = swz >> 8;
  const int b0 = (swz & 255) << 6;
  const int tid = threadIdx.x;
  const int w = tid >> 6, lane = tid & 63;
  const int c0l = lane & 15, hi = lane >> 4;
  const int u = w * 16 + c0l;

  const unsigned short* Wg = Wpk + (size_t)l0 * 131072 + (size_t)w * 16384 + lane * 8;
  bf16x8 wfr[4][8];
  #pragma unroll
  for (int q = 0; q < 4; q++)
    #pragma unroll
    for (int kt = 0; kt < 8; kt++)
      wfr[q][kt] = ld8(Wg + (q * 8 + kt) * 512);

  const float bI = bc[l0 * G4 + u];
  const float bF = bc[l0 * G4 + 128 + u];
  const float bG = bc[l0 * G4 + 256 + u];
  const float bO = bc[l0 * G4 + 384 + u];

  // zero h(-1) buffer (hl[1], read by t=0)
  for (int i = tid; i < 8192; i += 512) ((unsigned short*)hl)[8192 + i] = 0;

  // prologue DMA: obs tile of step 0 -> ol[0]. LDS dest is WAVE-uniform base:
  // wave w writes [base + w*1024B + lane*16B] -- the w*512 (shorts) offset is
  // mandatory (r13 bug: all 8 waves wrote the same 1KB -> NaN).
  {
    const int it0 = (0 == 4) ? l0 : (0 + (0 >= l0 ? 1 : 0));
    const unsigned short* src = obs_bf + ((size_t)it0 * BB + b0) * DD;
    __builtin_amdgcn_global_load_lds((const unsigned int*)(src + tid * 8),
                                     (unsigned int*)((unsigned short*)ol + w * 512), 16, 0, 0);
    __builtin_amdgcn_global_load_lds((const unsigned int*)(src + 4096 + tid * 8),
                                     (unsigned int*)((unsigned short*)ol + 4096 + w * 512), 16, 0, 0);
  }
  __syncthreads();   // covers zero-fill + prologue DMA (vmcnt drained)

  float creg[2][2][4];
  #pragma unroll
  for (int hh = 0; hh < 2; hh++)
    #pragma unroll
    for (int m2 = 0; m2 < 2; m2++)
      #pragma unroll
      for (int j = 0; j < 4; j++) creg[hh][m2][j] = 0.0f;

  for (int t = 0; t < 5; ++t) {
    const int it = (t == 4) ? l0 : (t + (t >= l0 ? 1 : 0));
    const int rbuf = (t + 1) & 1, wbuf = t & 1;
    const int ob_c = t & 1, ob_n = (t + 1) & 1;

    // issue DMA for obs[t+1] into ol[ob_n] (readers of that buffer finished
    // before the barrier ending step t-1)
    if (t < 4) {
      const int tn = t + 1;
      const int itn = (tn == 4) ? l0 : (tn + (tn >= l0 ? 1 : 0));
      const unsigned short* src = obs_bf + ((size_t)itn * BB + b0) * DD;
      unsigned short* dst = (unsigned short*)ol + ob_n * 8192 + w * 512;
      __builtin_amdgcn_global_load_lds((const unsigned int*)(src + tid * 8),
                                       (unsigned int*)dst, 16, 0, 0);
      __builtin_amdgcn_global_load_lds((const unsigned int*)(src + 4096 + tid * 8),
                                       (unsigned int*)(dst + 4096), 16, 0, 0);
    }

    #pragma unroll
    for (int hh = 0; hh < 2; hh++) {
      f32x4 acc[2][4];
      #pragma unroll
      for (int m2 = 0; m2 < 2; m2++)
        #pragma unroll
        for (int q = 0; q < 4; q++) acc[m2][q] = (f32x4){0, 0, 0, 0};

      // obs-part (kt 0..3) from ol[ob_c] (swizzled, conflict-free)
      #pragma unroll
      for (int kt = 0; kt < 4; ++kt) {
        bf16x8 a[2];
        #pragma unroll
        for (int m2 = 0; m2 < 2; m2++) {
          const int r = (hh * 2 + m2) * 16 + c0l;
          a[m2] = ld8(&ol[ob_c][r][(kt * 32 + hi * 8) ^ ((r & 7) << 3)]);
        }
        #pragma unroll
        for (int m2 = 0; m2 < 2; m2++)
          #pragma unroll
          for (int q = 0; q < 4; q++)
            acc[m2][q] = __builtin_amdgcn_mfma_f32_16x16x32_bf16(a[m2], wfr[q][kt], acc[m2][q], 0, 0, 0);
      }

      if (hh == 0) __syncthreads();   // hl[rbuf] from step t-1 certified

      // h-part (kt 4..7) from LDS
      #pragma unroll
      for (int kt = 4; kt < 8; ++kt) {
        bf16x8 a[2];
        #pragma unroll
        for (int m2 = 0; m2 < 2; m2++) {
          const int r = (hh * 2 + m2) * 16 + c0l;
          a[m2] = ld8(&hl[rbuf][r][((kt - 4) * 32 + hi * 8) ^ ((r & 7) << 3)]);
        }
        #pragma unroll
        for (int m2 = 0; m2 < 2; m2++)
          #pragma unroll
          for (int q = 0; q < 4; q++)
            acc[m2][q] = __builtin_amdgcn_mfma_f32_16x16x32_bf16(a[m2], wfr[q][kt], acc[m2][q], 0, 0, 0);
      }

      // epilogue
      #pragma unroll
      for (int m2 = 0; m2 < 2; m2++) {
        #pragma unroll
        for (int j = 0; j < 4; j++) {
          const int r = hh * 32 + m2 * 16 + hi * 4 + j;
          const float iv = acc[m2][0][j] + bI;
          const float fv = acc[m2][1][j] + bF;
          const float gv = acc[m2][2][j] + bG;
          const float ov = acc[m2][3][j] + bO;
          const float cn = sigf(fv) * creg[hh][m2][j] + sigf(iv) * tanhf_(gv);
          const float hn = sigf(ov) * tanhf_(cn);
          creg[hh][m2][j] = cn;
          hl[wbuf][r][u ^ ((r & 7) << 3)] = bf16r(hn);
        }
      }
    }
    __syncthreads();   // epi done; also drains this step's DMA (vmcnt 0)

    // coalesced wide copy hl[wbuf] -> cat
    unsigned short* catb = cat + ((size_t)it * BB + b0) * CATW + l0 * 128;
    #pragma unroll
    for (int cc = 0; cc < 2; ++cc) {
      const int idx = cc * 512 + tid;
      const int r = idx >> 4;
      const int c8 = (idx & 15) << 3;
      bf16x8 v = *(const bf16x8*)&hl[wbuf][r][c8 ^ ((r & 7) << 3)];
      *(bf16x8*)(catb + (size_t)r * CATW + c8) = v;
    }
  }
}

// ---------------- outs = cat @ d2_w^T + d2_b, 128 rows/block -----------------
__global__ __launch_bounds__(256) void k_d2(const unsigned short* __restrict__ cat,
                                            const unsigned short* __restrict__ d2w,
                                            const float* __restrict__ d2b,
                                            float* __restrict__ out)
{
  const int m0 = blockIdx.x * 128;
  const int w = threadIdx.x >> 6, l = threadIdx.x & 63;
  const int c0l = l & 15, hi = l >> 4;

  const unsigned short* arow0 = cat + (size_t)(m0 + w * 16 + c0l) * CATW;
  const unsigned short* arow1 = arow0 + (size_t)64 * CATW;
  f32x4 acc[2][4];
  #pragma unroll
  for (int mt = 0; mt < 2; mt++)
    #pragma unroll
    for (int nt = 0; nt < 4; nt++) acc[mt][nt] = (f32x4){0, 0, 0, 0};

  #pragma unroll 4
  for (int kt = 0; kt < 24; ++kt) {
    const int k = kt * 32 + hi * 8;
    bf16x8 a0 = ld8(arow0 + k);
    bf16x8 a1 = ld8(arow1 + k);
    #pragma unroll
    for (int nt = 0; nt < 4; nt++) {
      bf16x8 bfr = ld8(d2w + (size_t)(nt * 16 + c0l) * CATW + k);
      acc[0][nt] = __builtin_amdgcn_mfma_f32_16x16x32_bf16(a0, bfr, acc[0][nt], 0, 0, 0);
      acc[1][nt] = __builtin_amdgcn_mfma_f32_16x16x32_bf16(a1, bfr, acc[1][nt], 0, 0, 0);
    }
  }
  #pragma unroll
  for (int mt = 0; mt < 2; mt++) {
    #pragma unroll
    for (int nt = 0; nt < 4; nt++) {
      const int col = nt * 16 + c0l;
      const float bias = d2b[col];
      #pragma unroll
      for (int j = 0; j < 4; j++) {
        const int r = m0 + mt * 64 + w * 16 + hi * 4 + j;
        out[(size_t)r * AA + col] = acc[mt][nt][j] + bias;
      }
    }
  }
}

extern "C" void kernel_launch(void* const* d_in, const int* in_sizes, int n_in,
                              void* d_out, int out_size, void* d_ws, size_t ws_size,
                              hipStream_t stream)
{
  const float* input = (const float*)d_in[0];
  const float* h0    = (const float*)d_in[1];
  const float* c0    = (const float*)d_in[2];
  const float* d1w   = (const float*)d_in[3];
  const float* d1b   = (const float*)d_in[4];
  const float* d2w   = (const float*)d_in[5];
  const float* d2b   = (const float*)d_in[6];
  const float* mWih  = (const float*)d_in[7];
  const float* mWhh  = (const float*)d_in[8];
  const float* mbih  = (const float*)d_in[9];
  const float* mbhh  = (const float*)d_in[10];
  const float* cWih  = (const float*)d_in[11];
  const float* cWhh  = (const float*)d_in[12];
  const float* cbih  = (const float*)d_in[13];
  const float* cbhh  = (const float*)d_in[14];
  float* out = (float*)d_out;

  char* ws = (char*)d_ws;
  size_t off = 0;
  auto alloc = [&](size_t bytes) { void* p = ws + off; off += (bytes + 255) & ~255ull; return p; };
  unsigned short* d1w_bf = (unsigned short*)alloc(16384 * 2);
  unsigned short* d2w_bf = (unsigned short*)alloc(49152 * 2);
  unsigned short* Wm     = (unsigned short*)alloc(655360 * 2);
  unsigned short* Wcb    = (unsigned short*)alloc(655360 * 2);
  float* bm              = (float*)alloc(2560 * 4);
  float* bc              = (float*)alloc(2560 * 4);
  unsigned short* obs_bf = (unsigned short*)alloc((size_t)NAg * BB * DD * 2);
  unsigned short* cat    = (unsigned short*)alloc((size_t)NAg * BB * CATW * 2);

  float* out_h = out + (size_t)NAg * BB * AA;
  float* out_c = out_h + (size_t)NAg * BB * HH;

  k_prep<<<2048, 256, 0, stream>>>(d1w, d2w, mWih, mWhh, mbih, mbhh,
                                   cWih, cWhh, cbih, cbhh,
                                   d1w_bf, d2w_bf, Wm, Wcb, bm, bc);
  k_obs<<<(NAg * BB) / 64, 256, 0, stream>>>(input, d1w_bf, d1b, obs_bf);
  k_mem<<<(NAg * BB) / 64, 512, 0, stream>>>(obs_bf, h0, c0, Wm, bm, out_h, out_c, cat);
  k_comf<<<(NAg * BB) / 64, 512, 0, stream>>>(obs_bf, Wcb, bc, cat);
  k_d2<<<(NAg * BB) / 128, 256, 0, stream>>>(cat, d2w_bf, d2b, out);
}

// Round 16
// 328.506 us; speedup vs baseline: 1.2403x; 1.0175x over previous
//
#include <hip/hip_runtime.h>

#define BB   16384
#define NAg  5
#define DD   128
#define HH   128
#define G4   512   // 4*H
#define KC   256   // LS1 + H
#define AA   64
#define CATW 768   // 6*H

typedef __attribute__((ext_vector_type(8))) short bf16x8;
typedef __attribute__((ext_vector_type(4))) float f32x4;

#define DEV static __device__ __forceinline__

DEV unsigned short bf16r(float x){
  unsigned u = __float_as_uint(x);
  unsigned r = (u + 0x7fffu + ((u >> 16) & 1u)) >> 16;
  return (unsigned short)r;
}
// fast sigmoid/tanh: v_rcp_f32 (1 ULP) instead of IEEE division
DEV float sigf(float x){ return __builtin_amdgcn_rcpf(1.0f + __expf(-x)); }
DEV float tanhf_(float x){ return __builtin_fmaf(2.0f, __builtin_amdgcn_rcpf(1.0f + __expf(-2.0f * x)), -1.0f); }

DEV bf16x8 ld8(const unsigned short* p){ return *(const bf16x8*)p; }

DEV bf16x8 cvt8(const float* __restrict__ p){
  const float4* q = (const float4*)p;
  float4 v0 = q[0], v1 = q[1];
  bf16x8 r;
  r[0]=(short)bf16r(v0.x); r[1]=(short)bf16r(v0.y); r[2]=(short)bf16r(v0.z); r[3]=(short)bf16r(v0.w);
  r[4]=(short)bf16r(v1.x); r[5]=(short)bf16r(v1.y); r[6]=(short)bf16r(v1.z); r[7]=(short)bf16r(v1.w);
  return r;
}

// ---------------- prep: pack weights bf16; Wm/Wc -> per-wave reg-frag layout -
// [n][w][q][kt][lane][8]: lane holds W[g=q*128+w*16+(lane&15)][k=kt*32+(lane>>4)*8+e]
__global__ void k_prep(const float* __restrict__ d1w, const float* __restrict__ d2w,
                       const float* __restrict__ mWih, const float* __restrict__ mWhh,
                       const float* __restrict__ mbih, const float* __restrict__ mbhh,
                       const float* __restrict__ cWih, const float* __restrict__ cWhh,
                       const float* __restrict__ cbih, const float* __restrict__ cbhh,
                       unsigned short* d1w_bf, unsigned short* d2w_bf,
                       unsigned short* Wm, unsigned short* Wc, float* bm, float* bc)
{
  const long long TOT = 16384 + 49152 + 655360 + 655360 + 2560 + 2560;
  for (long long i = (long long)blockIdx.x * 256 + threadIdx.x; i < TOT;
       i += (long long)gridDim.x * 256) {
    long long x = i;
    if (x < 16384) { d1w_bf[x] = bf16r(d1w[x]); continue; }
    x -= 16384;
    if (x < 49152) { d2w_bf[x] = bf16r(d2w[x]); continue; }
    x -= 49152;
    if (x < 655360) {
      int e    = (int)(x & 7);
      int lane = (int)((x >> 3) & 63);
      int kt   = (int)((x >> 9) & 7);
      int q    = (int)((x >> 12) & 3);
      int w    = (int)((x >> 14) & 7);
      int n    = (int)(x >> 17);
      int g = q * 128 + w * 16 + (lane & 15);
      int k = kt * 32 + (lane >> 4) * 8 + e;
      Wm[x] = bf16r(k < 128 ? mWih[((size_t)n * 512 + g) * 128 + k]
                            : mWhh[((size_t)n * 512 + g) * 128 + (k - 128)]);
      continue;
    }
    x -= 655360;
    if (x < 655360) {
      int e    = (int)(x & 7);
      int lane = (int)((x >> 3) & 63);
      int kt   = (int)((x >> 9) & 7);
      int q    = (int)((x >> 12) & 3);
      int w    = (int)((x >> 14) & 7);
      int l0   = (int)(x >> 17);
      int g = q * 128 + w * 16 + (lane & 15);
      int k = kt * 32 + (lane >> 4) * 8 + e;
      Wc[x] = bf16r(k < 128 ? cWih[((size_t)l0 * 512 + g) * 128 + k]
                            : cWhh[((size_t)l0 * 512 + g) * 128 + (k - 128)]);
      continue;
    }
    x -= 655360;
    if (x < 2560) { bm[x] = mbih[x] + mbhh[x]; continue; }
    x -= 2560;
    bc[x] = cbih[x] + cbhh[x];
  }
}

// ---------------- fused obs-GEMM + mem-LSTM ----------------------------------
// Block (n, b0): computes obs tile (64 rows x 128) into LDS + global (swizzled
// layout), then runs the mem-LSTM step reading obs from LDS.
__global__ __launch_bounds__(512) void k_memobs(const float* __restrict__ input,
                                                const unsigned short* __restrict__ d1w,
                                                const float* __restrict__ d1b,
                                                const float* __restrict__ h0,
                                                const float* __restrict__ c0,
                                                const unsigned short* __restrict__ Wmp,
                                                const float* __restrict__ bm,
                                                float* __restrict__ out_h,
                                                float* __restrict__ out_c,
                                                unsigned short* __restrict__ cat,
                                                unsigned short* __restrict__ obs_bf)
{
  __shared__ __align__(16) unsigned short os[64][128];  // 16 KB obs bf16 (swizzled)
  __shared__ __align__(16) float hs[64][128];           // 32 KB f32 staging

  const int n = blockIdx.x >> 8;
  const int b0 = (blockIdx.x & 255) << 6;
  const int tid = threadIdx.x;
  const int w = tid >> 6, lane = tid & 63;
  const int c0l = lane & 15, hi = lane >> 4;
  const int u = w * 16 + c0l;

  // mem W fragments (resident)
  const unsigned short* Wg = Wmp + (size_t)n * 131072 + (size_t)w * 16384 + lane * 8;
  bf16x8 wfr[4][8];
  #pragma unroll
  for (int q = 0; q < 4; q++)
    #pragma unroll
    for (int kt = 0; kt < 8; kt++)
      wfr[q][kt] = ld8(Wg + (q * 8 + kt) * 512);

  // ---- obs phase: wave w computes d1-cols [w*16, w*16+16) for 64 rows ------
  f32x4 oacc[4];
  #pragma unroll
  for (int mt = 0; mt < 4; mt++) oacc[mt] = (f32x4){0, 0, 0, 0};

  #pragma unroll
  for (int kt = 0; kt < 4; ++kt) {
    const int k = kt * 32 + hi * 8;
    bf16x8 bfrD = ld8(d1w + (size_t)u * DD + k);       // d1w row u
    #pragma unroll
    for (int mt = 0; mt < 4; mt++) {
      const int br = b0 + mt * 16 + c0l;               // batch row
      bf16x8 a = cvt8(input + ((size_t)br * NAg + n) * DD + k);
      oacc[mt] = __builtin_amdgcn_mfma_f32_16x16x32_bf16(a, bfrD, oacc[mt], 0, 0, 0);
    }
  }
  {
    const float biasD = d1b[u];
    #pragma unroll
    for (int mt = 0; mt < 4; mt++) {
      #pragma unroll
      for (int j = 0; j < 4; j++) {
        const int r = mt * 16 + hi * 4 + j;
        os[r][u ^ ((r & 7) << 3)] = bf16r(oacc[mt][j] + biasD);
      }
    }
  }
  __syncthreads();
  // copy os -> obs_bf (linear store; global stays swizzled for k_comf's DMA)
  #pragma unroll
  for (int cc = 0; cc < 2; ++cc) {
    const int idx = cc * 512 + tid;
    const int r = idx >> 4;
    const int c8 = (idx & 15) << 3;
    bf16x8 v = *(const bf16x8*)&os[r][c8];
    *(bf16x8*)(obs_bf + ((size_t)n * BB + b0 + r) * DD + c8) = v;
  }

  // ---- mem-LSTM phase (obs from LDS) ---------------------------------------
  const float bI = bm[n * G4 + u];
  const float bF = bm[n * G4 + 128 + u];
  const float bG = bm[n * G4 + 256 + u];
  const float bO = bm[n * G4 + 384 + u];

  float cnr[2][2][4];

  #pragma unroll
  for (int hh = 0; hh < 2; hh++) {
    f32x4 acc[2][4];
    #pragma unroll
    for (int m2 = 0; m2 < 2; m2++)
      #pragma unroll
      for (int q = 0; q < 4; q++) acc[m2][q] = (f32x4){0, 0, 0, 0};

    #pragma unroll
    for (int kt = 0; kt < 8; ++kt) {
      bf16x8 a[2];
      #pragma unroll
      for (int m2 = 0; m2 < 2; m2++) {
        const int r = (hh * 2 + m2) * 16 + c0l;
        if (kt < 4) a[m2] = ld8(&os[r][(kt * 32 + hi * 8) ^ ((r & 7) << 3)]);
        else        a[m2] = cvt8(h0 + ((size_t)n * BB + b0 + r) * HH + (kt - 4) * 32 + hi * 8);
      }
      #pragma unroll
      for (int m2 = 0; m2 < 2; m2++)
        #pragma unroll
        for (int q = 0; q < 4; q++)
          acc[m2][q] = __builtin_amdgcn_mfma_f32_16x16x32_bf16(a[m2], wfr[q][kt], acc[m2][q], 0, 0, 0);
    }

    #pragma unroll
    for (int m2 = 0; m2 < 2; m2++) {
      #pragma unroll
      for (int j = 0; j < 4; j++) {
        const int r = hh * 32 + m2 * 16 + hi * 4 + j;
        const float iv = acc[m2][0][j] + bI;
        const float fv = acc[m2][1][j] + bF;
        const float gv = acc[m2][2][j] + bG;
        const float ov = acc[m2][3][j] + bO;
        const float cold = c0[((size_t)n * BB + b0 + r) * HH + u];
        const float cn = sigf(fv) * cold + sigf(iv) * tanhf_(gv);
        const float hn = sigf(ov) * tanhf_(cn);
        cnr[hh][m2][j] = cn;
        hs[r][u ^ ((r & 7) << 3)] = hn;
      }
    }
  }
  __syncthreads();
  // out_h copy (float4, full lines)
  #pragma unroll
  for (int cc = 0; cc < 4; ++cc) {
    const int idx = cc * 512 + tid;
    const int r = idx >> 5;
    const int c4 = (idx & 31) << 2;
    float4 v = *(const float4*)&hs[r][c4 ^ ((r & 7) << 3)];
    *(float4*)(out_h + ((size_t)n * BB + b0 + r) * HH + c4) = v;
  }
  // cat copy (bf16x8, full lines)
  #pragma unroll
  for (int cc = 0; cc < 2; ++cc) {
    const int idx = cc * 512 + tid;
    const int r = idx >> 4;
    const int c8 = (idx & 15) << 3;
    const float* p = &hs[r][c8 ^ ((r & 7) << 3)];
    float4 v0 = *(const float4*)p, v1 = *(const float4*)(p + 4);
    bf16x8 bv;
    bv[0]=(short)bf16r(v0.x); bv[1]=(short)bf16r(v0.y); bv[2]=(short)bf16r(v0.z); bv[3]=(short)bf16r(v0.w);
    bv[4]=(short)bf16r(v1.x); bv[5]=(short)bf16r(v1.y); bv[6]=(short)bf16r(v1.z); bv[7]=(short)bf16r(v1.w);
    *(bf16x8*)(cat + ((size_t)n * BB + b0 + r) * CATW + 640 + c8) = bv;
  }
  __syncthreads();
  // stage c and copy
  #pragma unroll
  for (int hh = 0; hh < 2; hh++)
    #pragma unroll
    for (int m2 = 0; m2 < 2; m2++)
      #pragma unroll
      for (int j = 0; j < 4; j++) {
        const int r = hh * 32 + m2 * 16 + hi * 4 + j;
        hs[r][u ^ ((r & 7) << 3)] = cnr[hh][m2][j];
      }
  __syncthreads();
  #pragma unroll
  for (int cc = 0; cc < 4; ++cc) {
    const int idx = cc * 512 + tid;
    const int r = idx >> 5;
    const int c4 = (idx & 31) << 2;
    float4 v = *(const float4*)&hs[r][c4 ^ ((r & 7) << 3)];
    *(float4*)(out_c + ((size_t)n * BB + b0 + r) * HH + c4) = v;
  }
}

// ---------------- fused com scan: reg-W + obs LDS prefetch (r14, unchanged) --
__global__ __launch_bounds__(512) void k_comf(const unsigned short* __restrict__ obs_bf,
                                              const unsigned short* __restrict__ Wpk,
                                              const float* __restrict__ bc,
                                              unsigned short* __restrict__ cat)
{
  __shared__ __align__(16) unsigned short hl[2][64][128];   // 32 KB
  __shared__ __align__(16) unsigned short ol[2][64][128];   // 32 KB obs dbuf

  const int bid = blockIdx.x;
  const int swz = (bid & 7) * 160 + (bid >> 3);   // 1280 = 8*160, bijective
  const int l0 = swz >> 8;
  const int b0 = (swz & 255) << 6;
  const int tid = threadIdx.x;
  const int w = tid >> 6, lane = tid & 63;
  const int c0l = lane & 15, hi = lane >> 4;
  const int u = w * 16 + c0l;

  const unsigned short* Wg = Wpk + (size_t)l0 * 131072 + (size_t)w * 16384 + lane * 8;
  bf16x8 wfr[4][8];
  #pragma unroll
  for (int q = 0; q < 4; q++)
    #pragma unroll
    for (int kt = 0; kt < 8; kt++)
      wfr[q][kt] = ld8(Wg + (q * 8 + kt) * 512);

  const float bI = bc[l0 * G4 + u];
  const float bF = bc[l0 * G4 + 128 + u];
  const float bG = bc[l0 * G4 + 256 + u];
  const float bO = bc[l0 * G4 + 384 + u];

  // zero h(-1) buffer (hl[1], read by t=0)
  for (int i = tid; i < 8192; i += 512) ((unsigned short*)hl)[8192 + i] = 0;

  // prologue DMA: obs tile of step 0 -> ol[0]; per-wave LDS base + w*512
  {
    const int it0 = (0 == 4) ? l0 : (0 + (0 >= l0 ? 1 : 0));
    const unsigned short* src = obs_bf + ((size_t)it0 * BB + b0) * DD;
    __builtin_amdgcn_global_load_lds((const unsigned int*)(src + tid * 8),
                                     (unsigned int*)((unsigned short*)ol + w * 512), 16, 0, 0);
    __builtin_amdgcn_global_load_lds((const unsigned int*)(src + 4096 + tid * 8),
                                     (unsigned int*)((unsigned short*)ol + 4096 + w * 512), 16, 0, 0);
  }
  __syncthreads();

  float creg[2][2][4];
  #pragma unroll
  for (int hh = 0; hh < 2; hh++)
    #pragma unroll
    for (int m2 = 0; m2 < 2; m2++)
      #pragma unroll
      for (int j = 0; j < 4; j++) creg[hh][m2][j] = 0.0f;

  for (int t = 0; t < 5; ++t) {
    const int it = (t == 4) ? l0 : (t + (t >= l0 ? 1 : 0));
    const int rbuf = (t + 1) & 1, wbuf = t & 1;
    const int ob_c = t & 1, ob_n = (t + 1) & 1;

    if (t < 4) {
      const int tn = t + 1;
      const int itn = (tn == 4) ? l0 : (tn + (tn >= l0 ? 1 : 0));
      const unsigned short* src = obs_bf + ((size_t)itn * BB + b0) * DD;
      unsigned short* dst = (unsigned short*)ol + ob_n * 8192 + w * 512;
      __builtin_amdgcn_global_load_lds((const unsigned int*)(src + tid * 8),
                                       (unsigned int*)dst, 16, 0, 0);
      __builtin_amdgcn_global_load_lds((const unsigned int*)(src + 4096 + tid * 8),
                                       (unsigned int*)(dst + 4096), 16, 0, 0);
    }

    #pragma unroll
    for (int hh = 0; hh < 2; hh++) {
      f32x4 acc[2][4];
      #pragma unroll
      for (int m2 = 0; m2 < 2; m2++)
        #pragma unroll
        for (int q = 0; q < 4; q++) acc[m2][q] = (f32x4){0, 0, 0, 0};

      #pragma unroll
      for (int kt = 0; kt < 4; ++kt) {
        bf16x8 a[2];
        #pragma unroll
        for (int m2 = 0; m2 < 2; m2++) {
          const int r = (hh * 2 + m2) * 16 + c0l;
          a[m2] = ld8(&ol[ob_c][r][(kt * 32 + hi * 8) ^ ((r & 7) << 3)]);
        }
        #pragma unroll
        for (int m2 = 0; m2 < 2; m2++)
          #pragma unroll
          for (int q = 0; q < 4; q++)
            acc[m2][q] = __builtin_amdgcn_mfma_f32_16x16x32_bf16(a[m2], wfr[q][kt], acc[m2][q], 0, 0, 0);
      }

      if (hh == 0) __syncthreads();   // hl[rbuf] from step t-1 certified

      #pragma unroll
      for (int kt = 4; kt < 8; ++kt) {
        bf16x8 a[2];
        #pragma unroll
        for (int m2 = 0; m2 < 2; m2++) {
          const int r = (hh * 2 + m2) * 16 + c0l;
          a[m2] = ld8(&hl[rbuf][r][((kt - 4) * 32 + hi * 8) ^ ((r & 7) << 3)]);
        }
        #pragma unroll
        for (int m2 = 0; m2 < 2; m2++)
          #pragma unroll
          for (int q = 0; q < 4; q++)
            acc[m2][q] = __builtin_amdgcn_mfma_f32_16x16x32_bf16(a[m2], wfr[q][kt], acc[m2][q], 0, 0, 0);
      }

      #pragma unroll
      for (int m2 = 0; m2 < 2; m2++) {
        #pragma unroll
        for (int j = 0; j < 4; j++) {
          const int r = hh * 32 + m2 * 16 + hi * 4 + j;
          const float iv = acc[m2][0][j] + bI;
          const float fv = acc[m2][1][j] + bF;
          const float gv = acc[m2][2][j] + bG;
          const float ov = acc[m2][3][j] + bO;
          const float cn = sigf(fv) * creg[hh][m2][j] + sigf(iv) * tanhf_(gv);
          const float hn = sigf(ov) * tanhf_(cn);
          creg[hh][m2][j] = cn;
          hl[wbuf][r][u ^ ((r & 7) << 3)] = bf16r(hn);
        }
      }
    }
    __syncthreads();

    unsigned short* catb = cat + ((size_t)it * BB + b0) * CATW + l0 * 128;
    #pragma unroll
    for (int cc = 0; cc < 2; ++cc) {
      const int idx = cc * 512 + tid;
      const int r = idx >> 4;
      const int c8 = (idx & 15) << 3;
      bf16x8 v = *(const bf16x8*)&hl[wbuf][r][c8 ^ ((r & 7) << 3)];
      *(bf16x8*)(catb + (size_t)r * CATW + c8) = v;
    }
  }
}

// ---------------- outs = cat @ d2_w^T + d2_b, 128 rows/block -----------------
__global__ __launch_bounds__(256) void k_d2(const unsigned short* __restrict__ cat,
                                            const unsigned short* __restrict__ d2w,
                                            const float* __restrict__ d2b,
                                            float* __restrict__ out)
{
  const int m0 = blockIdx.x * 128;
  const int w = threadIdx.x >> 6, l = threadIdx.x & 63;
  const int c0l = l & 15, hi = l >> 4;

  const unsigned short* arow0 = cat + (size_t)(m0 + w * 16 + c0l) * CATW;
  const unsigned short* arow1 = arow0 + (size_t)64 * CATW;
  f32x4 acc[2][4];
  #pragma unroll
  for (int mt = 0; mt < 2; mt++)
    #pragma unroll
    for (int nt = 0; nt < 4; nt++) acc[mt][nt] = (f32x4){0, 0, 0, 0};

  #pragma unroll 4
  for (int kt = 0; kt < 24; ++kt) {
    const int k = kt * 32 + hi * 8;
    bf16x8 a0 = ld8(arow0 + k);
    bf16x8 a1 = ld8(arow1 + k);
    #pragma unroll
    for (int nt = 0; nt < 4; nt++) {
      bf16x8 bfr = ld8(d2w + (size_t)(nt * 16 + c0l) * CATW + k);
      acc[0][nt] = __builtin_amdgcn_mfma_f32_16x16x32_bf16(a0, bfr, acc[0][nt], 0, 0, 0);
      acc[1][nt] = __builtin_amdgcn_mfma_f32_16x16x32_bf16(a1, bfr, acc[1][nt], 0, 0, 0);
    }
  }
  #pragma unroll
  for (int mt = 0; mt < 2; mt++) {
    #pragma unroll
    for (int nt = 0; nt < 4; nt++) {
      const int col = nt * 16 + c0l;
      const float bias = d2b[col];
      #pragma unroll
      for (int j = 0; j < 4; j++) {
        const int r = m0 + mt * 64 + w * 16 + hi * 4 + j;
        out[(size_t)r * AA + col] = acc[mt][nt][j] + bias;
      }
    }
  }
}

extern "C" void kernel_launch(void* const* d_in, const int* in_sizes, int n_in,
                              void* d_out, int out_size, void* d_ws, size_t ws_size,
                              hipStream_t stream)
{
  const float* input = (const float*)d_in[0];
  const float* h0    = (const float*)d_in[1];
  const float* c0    = (const float*)d_in[2];
  const float* d1w   = (const float*)d_in[3];
  const float* d1b   = (const float*)d_in[4];
  const float* d2w   = (const float*)d_in[5];
  const float* d2b   = (const float*)d_in[6];
  const float* mWih  = (const float*)d_in[7];
  const float* mWhh  = (const float*)d_in[8];
  const float* mbih  = (const float*)d_in[9];
  const float* mbhh  = (const float*)d_in[10];
  const float* cWih  = (const float*)d_in[11];
  const float* cWhh  = (const float*)d_in[12];
  const float* cbih  = (const float*)d_in[13];
  const float* cbhh  = (const float*)d_in[14];
  float* out = (float*)d_out;

  char* ws = (char*)d_ws;
  size_t off = 0;
  auto alloc = [&](size_t bytes) { void* p = ws + off; off += (bytes + 255) & ~255ull; return p; };
  unsigned short* d1w_bf = (unsigned short*)alloc(16384 * 2);
  unsigned short* d2w_bf = (unsigned short*)alloc(49152 * 2);
  unsigned short* Wm     = (unsigned short*)alloc(655360 * 2);
  unsigned short* Wcb    = (unsigned short*)alloc(655360 * 2);
  float* bm              = (float*)alloc(2560 * 4);
  float* bc              = (float*)alloc(2560 * 4);
  unsigned short* obs_bf = (unsigned short*)alloc((size_t)NAg * BB * DD * 2);
  unsigned short* cat    = (unsigned short*)alloc((size_t)NAg * BB * CATW * 2);

  float* out_h = out + (size_t)NAg * BB * AA;
  float* out_c = out_h + (size_t)NAg * BB * HH;

  k_prep<<<2048, 256, 0, stream>>>(d1w, d2w, mWih, mWhh, mbih, mbhh,
                                   cWih, cWhh, cbih, cbhh,
                                   d1w_bf, d2w_bf, Wm, Wcb, bm, bc);
  k_memobs<<<(NAg * BB) / 64, 512, 0, stream>>>(input, d1w_bf, d1b, h0, c0, Wm, bm,
                                                out_h, out_c, cat, obs_bf);
  k_comf<<<(NAg * BB) / 64, 512, 0, stream>>>(obs_bf, Wcb, bc, cat);
  k_d2<<<(NAg * BB) / 128, 256, 0, stream>>>(cat, d2w_bf, d2b, out);
}